// Round 2
// baseline (444.067 us; speedup 1.0000x reference)
//
#include <hip/hip_runtime.h>

// Problem constants
#define C_DIM   256
#define K_CODES 1024
#define HW      1024
#define NPOS    32768            // B*H*W
#define ZQ_ELEMS 8388608         // B*C*H*W

struct Cand { float s0, s1; int i0, i1; };   // top-2 (score, idx)

// workspace byte offsets
#define OFF_EF    0                          // 1024 floats (4096 B)
#define OFF_CAND  4096                       // 2*32768*16 = 1048576 B
#define OFF_IDX   (4096 + 1048576)           // 32768 ints
#define OFF_LIST  (OFF_IDX + 131072)         // 32768 ints
#define OFF_COUNT (OFF_LIST + 131072)        // 1 int (+pad)
#define OFF_LSUM  (OFF_COUNT + 8)            // 1 double

#define TAU 2e-4f   // fp32 margin below which we re-score the row with faithful fp32 semantics

__global__ void k0_init(int* count, double* lsum) {
    *count = 0;
    *lsum = 0.0;
}

// ||e_k||^2 exactly as numpy fp32 pairwise-sum of the pre-rounded squares:
// n=256 -> pw(128)+pw(128); pw(128) = 8 accumulators unrolled, combined
// ((r0+r1)+(r2+r3))+((r4+r5)+(r6+r7)). No FMA contraction allowed.
__global__ __launch_bounds__(256) void k1_enorm(const float* __restrict__ emb,
                                                float* __restrict__ Ef) {
    const int k = blockIdx.x * 256 + threadIdx.x;
    const float* a = emb + (size_t)k * C_DIM;
    float blk[2];
#pragma unroll
    for (int h = 0; h < 2; ++h) {
        const float* p = a + h * 128;
        float4 v0 = *reinterpret_cast<const float4*>(p);
        float4 v1 = *reinterpret_cast<const float4*>(p + 4);
        float r[8];
        r[0] = __fmul_rn(v0.x, v0.x); r[1] = __fmul_rn(v0.y, v0.y);
        r[2] = __fmul_rn(v0.z, v0.z); r[3] = __fmul_rn(v0.w, v0.w);
        r[4] = __fmul_rn(v1.x, v1.x); r[5] = __fmul_rn(v1.y, v1.y);
        r[6] = __fmul_rn(v1.z, v1.z); r[7] = __fmul_rn(v1.w, v1.w);
        for (int i = 8; i < 128; i += 8) {
            float4 w0 = *reinterpret_cast<const float4*>(p + i);
            float4 w1 = *reinterpret_cast<const float4*>(p + i + 4);
            r[0] = __fadd_rn(r[0], __fmul_rn(w0.x, w0.x));
            r[1] = __fadd_rn(r[1], __fmul_rn(w0.y, w0.y));
            r[2] = __fadd_rn(r[2], __fmul_rn(w0.z, w0.z));
            r[3] = __fadd_rn(r[3], __fmul_rn(w0.w, w0.w));
            r[4] = __fadd_rn(r[4], __fmul_rn(w1.x, w1.x));
            r[5] = __fadd_rn(r[5], __fmul_rn(w1.y, w1.y));
            r[6] = __fadd_rn(r[6], __fmul_rn(w1.z, w1.z));
            r[7] = __fadd_rn(r[7], __fmul_rn(w1.w, w1.w));
        }
        blk[h] = __fadd_rn(__fadd_rn(__fadd_rn(r[0], r[1]), __fadd_rn(r[2], r[3])),
                           __fadd_rn(__fadd_rn(r[4], r[5]), __fadd_rn(r[6], r[7])));
    }
    Ef[k] = __fadd_rn(blk[0], blk[1]);
}

// Main scoring GEMM: block = 128 positions x 512 codes (one half of K).
// 256 threads, 8x8 micro-tile, fp32 sequential-FMA accumulation over c=0..255.
// Emits per-(row,half) top-2 candidates (score WITHOUT the +||z||^2 offset).
__global__ __launch_bounds__(256) void k2_score(const float* __restrict__ z,
                                                const float* __restrict__ emb,
                                                const float* __restrict__ Ef,
                                                Cand* __restrict__ cand) {
    __shared__ __align__(16) float smem[8192];   // 32 KB: zs[32][128] | es[32][128]
    float* zs = smem;
    float* es = smem + 4096;

    const int t  = threadIdx.x;
    const int tx = t & 15, ty = t >> 4;
    const int pos0 = blockIdx.x * 128;
    const int b    = pos0 >> 10;
    const int hw0  = pos0 & 1023;
    const int half = blockIdx.y;
    const float* zbase = z + (size_t)b * C_DIM * HW + hw0;

    float best[8], sec[8];
    int   bi[8],  si[8];
#pragma unroll
    for (int i = 0; i < 8; ++i) { best[i] = 1e30f; sec[i] = 1e30f; bi[i] = 1 << 29; si[i] = 1 << 29; }

    const int zcc = t >> 3, zxo = (t & 7) * 16;   // z tile load role
    const int ek  = t >> 1, ech = (t & 1) * 16;   // emb tile load role

    for (int kt = 0; kt < 4; ++kt) {
        const int k0 = half * 512 + kt * 128;
        float acc[2][2][4][4];
#pragma unroll
        for (int a0 = 0; a0 < 2; ++a0)
#pragma unroll
        for (int a1 = 0; a1 < 2; ++a1)
#pragma unroll
        for (int a2 = 0; a2 < 4; ++a2)
#pragma unroll
        for (int a3 = 0; a3 < 4; ++a3) acc[a0][a1][a2][a3] = 0.f;

        for (int c0 = 0; c0 < C_DIM; c0 += 32) {
            {
                const float* zp = zbase + (size_t)(c0 + zcc) * HW + zxo;
                float4 v0 = *reinterpret_cast<const float4*>(zp + 0);
                float4 v1 = *reinterpret_cast<const float4*>(zp + 4);
                float4 v2 = *reinterpret_cast<const float4*>(zp + 8);
                float4 v3 = *reinterpret_cast<const float4*>(zp + 12);
                *reinterpret_cast<float4*>(&zs[zcc * 128 + zxo + 0])  = v0;
                *reinterpret_cast<float4*>(&zs[zcc * 128 + zxo + 4])  = v1;
                *reinterpret_cast<float4*>(&zs[zcc * 128 + zxo + 8])  = v2;
                *reinterpret_cast<float4*>(&zs[zcc * 128 + zxo + 12]) = v3;
            }
            {
                const float* ep = emb + (size_t)(k0 + ek) * C_DIM + c0 + ech;
                float4 e0 = *reinterpret_cast<const float4*>(ep + 0);
                float4 e1 = *reinterpret_cast<const float4*>(ep + 4);
                float4 e2 = *reinterpret_cast<const float4*>(ep + 8);
                float4 e3 = *reinterpret_cast<const float4*>(ep + 12);
                es[(ech + 0)  * 128 + ek] = e0.x; es[(ech + 1)  * 128 + ek] = e0.y;
                es[(ech + 2)  * 128 + ek] = e0.z; es[(ech + 3)  * 128 + ek] = e0.w;
                es[(ech + 4)  * 128 + ek] = e1.x; es[(ech + 5)  * 128 + ek] = e1.y;
                es[(ech + 6)  * 128 + ek] = e1.z; es[(ech + 7)  * 128 + ek] = e1.w;
                es[(ech + 8)  * 128 + ek] = e2.x; es[(ech + 9)  * 128 + ek] = e2.y;
                es[(ech + 10) * 128 + ek] = e2.z; es[(ech + 11) * 128 + ek] = e2.w;
                es[(ech + 12) * 128 + ek] = e3.x; es[(ech + 13) * 128 + ek] = e3.y;
                es[(ech + 14) * 128 + ek] = e3.z; es[(ech + 15) * 128 + ek] = e3.w;
            }
            __syncthreads();
#pragma unroll 4
            for (int cc = 0; cc < 32; ++cc) {
                const float4 a0 = *reinterpret_cast<const float4*>(&zs[cc * 128 + ty * 4]);
                const float4 a1 = *reinterpret_cast<const float4*>(&zs[cc * 128 + 64 + ty * 4]);
                const float4 b0 = *reinterpret_cast<const float4*>(&es[cc * 128 + tx * 4]);
                const float4 b1 = *reinterpret_cast<const float4*>(&es[cc * 128 + 64 + tx * 4]);
                const float A[2][4]  = {{a0.x, a0.y, a0.z, a0.w}, {a1.x, a1.y, a1.z, a1.w}};
                const float Bv[2][4] = {{b0.x, b0.y, b0.z, b0.w}, {b1.x, b1.y, b1.z, b1.w}};
#pragma unroll
                for (int gi = 0; gi < 2; ++gi)
#pragma unroll
                for (int ii = 0; ii < 4; ++ii)
#pragma unroll
                for (int gj = 0; gj < 2; ++gj)
#pragma unroll
                for (int jj = 0; jj < 4; ++jj)
                    acc[gi][gj][ii][jj] = __fmaf_rn(A[gi][ii], Bv[gj][jj], acc[gi][gj][ii][jj]);
            }
            __syncthreads();
        }

        float efv[8];
#pragma unroll
        for (int gj = 0; gj < 2; ++gj)
#pragma unroll
        for (int jj = 0; jj < 4; ++jj)
            efv[gj * 4 + jj] = Ef[k0 + gj * 64 + tx * 4 + jj];

#pragma unroll
        for (int gi = 0; gi < 2; ++gi)
#pragma unroll
        for (int ii = 0; ii < 4; ++ii) {
            const int slot = gi * 4 + ii;
            float bb = best[slot], ssc = sec[slot];
            int bbi = bi[slot], ssi = si[slot];
#pragma unroll
            for (int gj = 0; gj < 2; ++gj)
#pragma unroll
            for (int jj = 0; jj < 4; ++jj) {
                const int kk = k0 + gj * 64 + tx * 4 + jj;
                const float s = efv[gj * 4 + jj] - 2.0f * acc[gi][gj][ii][jj];
                if (s < bb)       { ssc = bb; ssi = bbi; bb = s; bbi = kk; }
                else if (s < ssc) { ssc = s; ssi = kk; }
            }
            best[slot] = bb; sec[slot] = ssc; bi[slot] = bbi; si[slot] = ssi;
        }
    }

    __syncthreads();
    Cand* csh = reinterpret_cast<Cand*>(smem);
#pragma unroll
    for (int gi = 0; gi < 2; ++gi)
#pragma unroll
    for (int ii = 0; ii < 4; ++ii) {
        const int slot = gi * 4 + ii;
        const int pos = gi * 64 + ty * 4 + ii;
        Cand c; c.s0 = best[slot]; c.s1 = sec[slot]; c.i0 = bi[slot]; c.i1 = si[slot];
        csh[pos * 16 + tx] = c;
    }
    __syncthreads();
    for (int st = 8; st > 0; st >>= 1) {
        if (tx < st) {
#pragma unroll
            for (int gi = 0; gi < 2; ++gi)
#pragma unroll
            for (int ii = 0; ii < 4; ++ii) {
                const int pos = gi * 64 + ty * 4 + ii;
                Cand a = csh[pos * 16 + tx];
                Cand c = csh[pos * 16 + tx + st];
                if (c.s0 < a.s0 || (c.s0 == a.s0 && c.i0 < a.i0)) {
                    a.s1 = a.s0; a.i1 = a.i0; a.s0 = c.s0; a.i0 = c.i0;
                } else if (c.s0 < a.s1 || (c.s0 == a.s1 && c.i0 < a.i1)) {
                    a.s1 = c.s0; a.i1 = c.i0;
                }
                if (c.s1 < a.s1 || (c.s1 == a.s1 && c.i1 < a.i1)) { a.s1 = c.s1; a.i1 = c.i1; }
                csh[pos * 16 + tx] = a;
            }
        }
        __syncthreads();
    }
    if (tx == 0) {
#pragma unroll
        for (int gi = 0; gi < 2; ++gi)
#pragma unroll
        for (int ii = 0; ii < 4; ++ii) {
            const int pos = gi * 64 + ty * 4 + ii;
            cand[(size_t)half * NPOS + pos0 + pos] = csh[pos * 16];
        }
    }
}

// merge halves, emit provisional index, flag close rows for faithful re-score
__global__ __launch_bounds__(256) void k3a_decide(const Cand* __restrict__ cand,
                                                  int* __restrict__ idxf,
                                                  int* __restrict__ list,
                                                  int* __restrict__ count) {
    const int r = blockIdx.x * 256 + threadIdx.x;
    Cand a = cand[r];
    const Cand c = cand[NPOS + r];
    if (c.s0 < a.s0 || (c.s0 == a.s0 && c.i0 < a.i0)) {
        a.s1 = a.s0; a.i1 = a.i0; a.s0 = c.s0; a.i0 = c.i0;
    } else if (c.s0 < a.s1 || (c.s0 == a.s1 && c.i0 < a.i1)) {
        a.s1 = c.s0; a.i1 = c.i0;
    }
    if (c.s1 < a.s1 || (c.s1 == a.s1 && c.i1 < a.i1)) { a.s1 = c.s1; a.i1 = c.i1; }
    idxf[r] = a.i0;
    if (a.s1 - a.s0 < TAU) {
        const int p = atomicAdd(count, 1);
        list[p] = r;
    }
}

// Faithful fp32 re-score of flagged rows, emulating the numpy float32 pipeline:
//   zn = pairwise-sum fp32 of rounded squares (numpy algorithm, n=256)
//   dot_k = sequential FMA chain over c = 0..255 (BLAS sgemm semantics)
//   d_k = fl( fl(zn + en_k) - fl(2*dot_k) );  argmin first-index-wins.
__global__ __launch_bounds__(256) void k3b_refine(const float* __restrict__ z,
                                                  const float* __restrict__ emb,
                                                  const float* __restrict__ Ef,
                                                  const int* __restrict__ list,
                                                  const int* __restrict__ count,
                                                  int* __restrict__ idxf) {
    __shared__ float zsh[C_DIM];
    __shared__ float sZn;
    __shared__ float rd[256];
    __shared__ int   ri[256];
    const int t = threadIdx.x;
    const int cnt = *count;
    for (int li = blockIdx.x; li < cnt; li += gridDim.x) {
        const int r = list[li];
        const int b = r >> 10, hw = r & 1023;
        zsh[t] = z[((size_t)b * C_DIM + t) * HW + hw];
        __syncthreads();
        if (t == 0) {
            float blk[2];
#pragma unroll
            for (int h = 0; h < 2; ++h) {
                const float* p = zsh + h * 128;
                float rr[8];
#pragma unroll
                for (int j = 0; j < 8; ++j) rr[j] = __fmul_rn(p[j], p[j]);
                for (int i = 8; i < 128; i += 8) {
#pragma unroll
                    for (int j = 0; j < 8; ++j)
                        rr[j] = __fadd_rn(rr[j], __fmul_rn(p[i + j], p[i + j]));
                }
                blk[h] = __fadd_rn(__fadd_rn(__fadd_rn(rr[0], rr[1]), __fadd_rn(rr[2], rr[3])),
                                   __fadd_rn(__fadd_rn(rr[4], rr[5]), __fadd_rn(rr[6], rr[7])));
            }
            sZn = __fadd_rn(blk[0], blk[1]);
        }
        __syncthreads();
        const float zn = sZn;
        float bd = 1e30f; int bidx = 1 << 29;
#pragma unroll
        for (int q = 0; q < 4; ++q) {
            const int code = t * 4 + q;
            const float* e = emb + (size_t)code * C_DIM;
            float acc = 0.f;
            for (int c = 0; c < C_DIM; c += 4) {
                const float4 ev = *reinterpret_cast<const float4*>(e + c);
                acc = __fmaf_rn(zsh[c + 0], ev.x, acc);
                acc = __fmaf_rn(zsh[c + 1], ev.y, acc);
                acc = __fmaf_rn(zsh[c + 2], ev.z, acc);
                acc = __fmaf_rn(zsh[c + 3], ev.w, acc);
            }
            const float dk = __fsub_rn(__fadd_rn(zn, Ef[code]), __fmul_rn(2.0f, acc));
            if (dk < bd) { bd = dk; bidx = code; }   // ascending code, strict < = first-wins
        }
        rd[t] = bd; ri[t] = bidx;
        __syncthreads();
        for (int st = 128; st > 0; st >>= 1) {
            if (t < st) {
                if (rd[t + st] < rd[t] || (rd[t + st] == rd[t] && ri[t + st] < ri[t])) {
                    rd[t] = rd[t + st]; ri[t] = ri[t + st];
                }
            }
            __syncthreads();
        }
        if (t == 0) idxf[r] = ri[0];
        __syncthreads();
    }
}

// write zq (straight-through fp32) + fp64 loss partial
__global__ __launch_bounds__(256) void k4_out(const float* __restrict__ z,
                                              const float* __restrict__ emb,
                                              const int* __restrict__ idxf,
                                              float* __restrict__ out,
                                              double* __restrict__ lsum) {
    const size_t stride = (size_t)gridDim.x * 256;
    double acc = 0.0;
    for (size_t v = (size_t)blockIdx.x * 256 + threadIdx.x; v < (ZQ_ELEMS / 4); v += stride) {
        const size_t e = v * 4;
        const int hw = (int)(e & 1023);
        const int bc = (int)(e >> 10);
        const int c  = bc & 255;
        const int b  = bc >> 8;
        const int n  = b * 1024 + hw;
        const float4 zv = *reinterpret_cast<const float4*>(z + e);
        const int j0 = idxf[n], j1 = idxf[n + 1], j2 = idxf[n + 2], j3 = idxf[n + 3];
        const float e0 = emb[(size_t)j0 * C_DIM + c];
        const float e1 = emb[(size_t)j1 * C_DIM + c];
        const float e2 = emb[(size_t)j2 * C_DIM + c];
        const float e3 = emb[(size_t)j3 * C_DIM + c];
        float4 o;
        o.x = zv.x + (e0 - zv.x);
        o.y = zv.y + (e1 - zv.y);
        o.z = zv.z + (e2 - zv.z);
        o.w = zv.w + (e3 - zv.w);
        *reinterpret_cast<float4*>(out + e) = o;
        const double d0 = (double)e0 - (double)zv.x;
        const double d1 = (double)e1 - (double)zv.y;
        const double d2 = (double)e2 - (double)zv.z;
        const double d3 = (double)e3 - (double)zv.w;
        acc += d0 * d0 + d1 * d1 + d2 * d2 + d3 * d3;
    }
#pragma unroll
    for (int off = 32; off > 0; off >>= 1) acc += __shfl_down(acc, off);
    __shared__ double wsum[4];
    const int w = threadIdx.x >> 6, lane = threadIdx.x & 63;
    if (lane == 0) wsum[w] = acc;
    __syncthreads();
    if (threadIdx.x == 0) atomicAdd(lsum, wsum[0] + wsum[1] + wsum[2] + wsum[3]);
}

__global__ __launch_bounds__(256) void k5_idx(const int* __restrict__ idxf,
                                              float* __restrict__ out) {
    const int n = blockIdx.x * 256 + threadIdx.x;
    out[(size_t)ZQ_ELEMS + 3 + n] = (float)idxf[n];
}

__global__ void k6_loss(const double* __restrict__ lsum, float* __restrict__ out) {
    const double m = *lsum / (double)ZQ_ELEMS;
    const float cm = (float)(0.25 * m);
    const float cb = (float)m;
    out[ZQ_ELEMS]     = cm + cb;   // loss
    out[ZQ_ELEMS + 1] = cm;        // commitment
    out[ZQ_ELEMS + 2] = cb;        // codebook
}

extern "C" void kernel_launch(void* const* d_in, const int* in_sizes, int n_in,
                              void* d_out, int out_size, void* d_ws, size_t ws_size,
                              hipStream_t stream) {
    const float* z   = (const float*)d_in[0];
    const float* emb = (const float*)d_in[1];
    float* out = (float*)d_out;
    char* ws = (char*)d_ws;

    float*  Ef    = (float*)(ws + OFF_EF);
    Cand*   cand  = (Cand*)(ws + OFF_CAND);
    int*    idxf  = (int*)(ws + OFF_IDX);
    int*    list  = (int*)(ws + OFF_LIST);
    int*    count = (int*)(ws + OFF_COUNT);
    double* lsum  = (double*)(ws + OFF_LSUM);

    k0_init<<<1, 1, 0, stream>>>(count, lsum);
    k1_enorm<<<4, 256, 0, stream>>>(emb, Ef);
    k2_score<<<dim3(256, 2), 256, 0, stream>>>(z, emb, Ef, cand);
    k3a_decide<<<128, 256, 0, stream>>>(cand, idxf, list, count);
    k3b_refine<<<256, 256, 0, stream>>>(z, emb, Ef, list, count, idxf);
    k4_out<<<2048, 256, 0, stream>>>(z, emb, idxf, out, lsum);
    k5_idx<<<128, 256, 0, stream>>>(idxf, out);
    k6_loss<<<1, 1, 0, stream>>>(lsum, out);
}